// Round 20
// baseline (722.189 us; speedup 1.0000x reference)
//
#include <hip/hip_runtime.h>
#include <hip/hip_bf16.h>

#define NB   8
#define SS   2048
#define DD   1024
#define DFFN 4096
#define MTOT (NB*SS)   // 16384

typedef unsigned short u16;
typedef __attribute__((ext_vector_type(4))) float f32x4;
typedef __attribute__((ext_vector_type(8))) short bf16x8;
typedef __attribute__((ext_vector_type(4))) int i32x4;
typedef __attribute__((ext_vector_type(4))) unsigned short u16x4;
typedef __attribute__((ext_vector_type(8))) unsigned short u16x8;

__device__ __forceinline__ u16 f2bf(float f) {
  union { float f; unsigned u; } c; c.f = f;
  unsigned r = c.u + 0x7FFFu + ((c.u >> 16) & 1u);
  return (u16)(r >> 16);
}

__device__ __forceinline__ void gload16(const void* g, void* l) {
  __builtin_amdgcn_global_load_lds(
      (const __attribute__((address_space(1))) void*)(unsigned long long)g,
      (__attribute__((address_space(3))) void*)(unsigned)(unsigned long long)l,
      16, 0, 0);
}

// opaque ds_read_b128 (manual lgkmcnt/vmcnt accounting)
__device__ __forceinline__ bf16x8 dsr128(unsigned addr) {
  i32x4 r;
  asm volatile("ds_read_b128 %0, %1" : "=v"(r) : "v"(addr));
  return __builtin_bit_cast(bf16x8, r);
}

// ---------------------------------------------------------------------------
// Champion (R17, 677us): 128x128 GEMM-BT, 4 waves (2x2), per-wave 64x64,
// BK=32, 3-buffer LDS ring (48KB), stage t+2, counted vmcnt(4). Swizzled
// staging, LDS-staged epilogue, bijective XCD swizzle + width-4 supertile.
// OUTMODE: 0=bf16, 1=f32, 2=f16, 3=QKV fused.
// ---------------------------------------------------------------------------
template<int EBIAS, int EGELU, int ESCALE, int EROWSCALE, int OUTMODE, int CSKIP, int CK>
__global__ __launch_bounds__(256, 4)
void gemm128(const u16* __restrict__ A, const u16* __restrict__ B,
             const float* __restrict__ bias0, const float* __restrict__ bias1,
             const float* __restrict__ bias2, const float* __restrict__ rowscale,
             void* __restrict__ C0, void* __restrict__ C1, void* __restrict__ C2,
             int K, int lda, int ldb, int ldc, float scale,
             long long sA, long long sB, long long sC, int sRS)
{
  __shared__ __align__(1024) u16 smem[24576];   // 48 KB

  const int gx = gridDim.x, gy = gridDim.y;
  const int nwg = gx * gy;
  const int orig = blockIdx.y * gx + blockIdx.x;
  const int q = nwg >> 3, r = nwg & 7;
  const int xcd = orig & 7, pos0 = orig >> 3;
  const int wg = (xcd < r ? xcd * (q + 1) : r * (q + 1) + (xcd - r) * q) + pos0;
  int bx, by;
  if ((gx & 3) == 0) {
    const int rr = wg % (gy << 2);
    bx = (wg / (gy << 2)) * 4 + (rr & 3);
    by = rr >> 2;
  } else {
    bx = wg % gx; by = wg / gx;
  }
  const int row0 = by * 128, col0 = bx * 128;
  if (CSKIP && col0 > row0 + 127) return;

  const int z = blockIdx.z;
  A += (size_t)z * sA;
  B += (size_t)z * sB;

  int nkt = K >> 5;
  if (CK) { int lim = (row0 + 128) >> 5; if (lim < nkt) nkt = lim; }

  const int tid  = threadIdx.x;
  const int wid  = tid >> 6;
  const int lane = tid & 63;
  const int wr = wid >> 1, wc = wid & 1;

  const int srow = wid * 16 + (lane >> 2);
  const int sunit = (lane & 3) ^ ((lane >> 3) & 3);
  const char* gA = (const char*)A + ((size_t)(row0 + srow) * lda + sunit * 8) * 2;
  const char* gB = (const char*)B + ((size_t)(col0 + srow) * ldb + sunit * 8) * 2;
  const size_t ldab = (size_t)64 * lda * 2;
  const size_t ldbb = (size_t)64 * ldb * 2;

  #define STG(t2, bo) { char* lb = (char*)smem + (bo); size_t kb = (size_t)(t2) * 64; \
      gload16(gA + kb,        lb + wid * 1024);                                       \
      gload16(gA + kb + ldab, lb + 4096 + wid * 1024);                                \
      gload16(gB + kb,        lb + 8192 + wid * 1024);                                \
      gload16(gB + kb + ldbb, lb + 8192 + 4096 + wid * 1024); }

  const int fr = lane & 15;
  const int ks16 = ((lane >> 4) & 3) * 16;
  const int xm = ((lane >> 1) & 3) << 4;
  const unsigned sbase = (unsigned)(unsigned long long)(void*)smem;

  f32x4 acc[4][4] = {};

  STG(0, 0); STG(1, 16384);
  asm volatile("s_waitcnt vmcnt(4)");
  asm volatile("s_barrier" ::: "memory");

  unsigned cbo = 0, sbo = 32768;

  #define KSTEP_BODY(WAITN)                                                    \
    bf16x8 af[4], bf[4];                                                       \
    _Pragma("unroll") for (int m = 0; m < 4; ++m)                              \
      af[m] = dsr128(sbase + cbo + (((wr * 64 + m * 16 + fr) * 64 + ks16) ^ xm)); \
    _Pragma("unroll") for (int n = 0; n < 4; ++n)                              \
      bf[n] = dsr128(sbase + cbo + ((8192 + (wc * 64 + n * 16 + fr) * 64 + ks16) ^ xm)); \
    asm volatile("s_waitcnt lgkmcnt(0)");                                      \
    __builtin_amdgcn_sched_barrier(0);                                         \
    __builtin_amdgcn_s_setprio(1);                                             \
    _Pragma("unroll") for (int m = 0; m < 4; ++m)                              \
      _Pragma("unroll") for (int n = 0; n < 4; ++n)                            \
        acc[m][n] = __builtin_amdgcn_mfma_f32_16x16x32_bf16(af[m], bf[n], acc[m][n], 0, 0, 0); \
    __builtin_amdgcn_s_setprio(0);                                             \
    asm volatile("s_waitcnt vmcnt(" #WAITN ")");                               \
    asm volatile("s_barrier" ::: "memory");                                    \
    cbo += 16384; if (cbo == 49152) cbo = 0;                                   \
    sbo += 16384; if (sbo == 49152) sbo = 0;

  for (int t = 0; t < nkt - 2; ++t) {
    STG(t + 2, sbo);
    KSTEP_BODY(4)
  }
  { KSTEP_BODY(0) }
  { KSTEP_BODY(0) }
  #undef KSTEP_BODY
  #undef STG

  // ---- epilogue via LDS ----
  char* sm = (char*)smem;
  const int r4 = (lane >> 4) * 4;
  const int sel  = (OUTMODE == 3) ? (col0 >> 10) : 0;
  const int oc0  = (OUTMODE == 3) ? (col0 & 1023) : col0;
  const float* bias = (OUTMODE == 3) ? (sel == 0 ? bias0 : sel == 1 ? bias1 : bias2)
                                     : bias0;

  if (OUTMODE == 1) {
#pragma unroll
    for (int p = 0; p < 2; ++p) {
      if (wc == p) {
#pragma unroll
        for (int n = 0; n < 4; ++n) {
          const int col = oc0 + wc * 64 + n * 16 + fr;
          const int pb = (n * 16 + fr) * 4;
          float bia = EBIAS ? bias[col] : 0.0f;
#pragma unroll
          for (int m = 0; m < 4; ++m) {
#pragma unroll
            for (int j = 0; j < 4; ++j) {
              const int line = wr * 64 + m * 16 + r4 + j;
              float xv = acc[m][n][j];
              if (EBIAS)     xv += bia;
              if (ESCALE)    xv *= scale;
              if (EROWSCALE) xv *= rowscale[z * sRS + row0 + line];
              if (EGELU)     xv = 0.5f * xv * (1.0f + erff(xv * 0.70710678118f));
              *(float*)(sm + ((line * 256 + pb) ^ ((line & 7) << 4))) = xv;
            }
          }
        }
      }
      __syncthreads();
      float* Cb = (float*)C0 + (size_t)z * sC;
#pragma unroll
      for (int i = 0; i < 8; ++i) {
        const int o = i * 4096 + tid * 16;
        const int line = o >> 8, ps = o & 255;
        f32x4 v = *(const f32x4*)(sm + ((line * 256 + ps) ^ ((line & 7) << 4)));
        *(f32x4*)((char*)(Cb + (size_t)(row0 + line) * ldc + oc0 + p * 64) + ps) = v;
      }
      __syncthreads();
    }
  } else if (OUTMODE == 3 && sel == 2) {
#pragma unroll
    for (int n = 0; n < 4; ++n) {
      const int line = wc * 64 + n * 16 + fr;
      float bia = EBIAS ? bias[oc0 + line] : 0.0f;
#pragma unroll
      for (int m = 0; m < 4; ++m) {
        const int rb = wr * 64 + m * 16 + r4;
        u16x4 pk;
#pragma unroll
        for (int j = 0; j < 4; ++j) pk[j] = f2bf(acc[m][n][j] + bia);
        *(u16x4*)(sm + ((line * 256 + rb * 2) ^ ((line & 7) << 4))) = pk;
      }
    }
    __syncthreads();
    u16* Cb = (u16*)C2 + (size_t)(row0 >> 11) * (DD * SS) + (row0 & (SS - 1));
#pragma unroll
    for (int i = 0; i < 8; ++i) {
      const int o = i * 4096 + tid * 16;
      const int line = o >> 8, ps = o & 255;
      f32x4 v = *(const f32x4*)(sm + ((line * 256 + ps) ^ ((line & 7) << 4)));
      *(f32x4*)((char*)(Cb + (size_t)(oc0 + line) * SS) + ps) = v;
    }
  } else {
#pragma unroll
    for (int n = 0; n < 4; ++n) {
      const int col = oc0 + wc * 64 + n * 16 + fr;
      const int pc = (wc * 64 + n * 16 + fr) * 2;
      float bia = EBIAS ? bias[col] : 0.0f;
#pragma unroll
      for (int m = 0; m < 4; ++m) {
#pragma unroll
        for (int j = 0; j < 4; ++j) {
          const int line = wr * 64 + m * 16 + r4 + j;
          float xv = acc[m][n][j];
          if (EBIAS)     xv += bia;
          if (ESCALE)    xv *= scale;
          if (EROWSCALE) xv *= rowscale[z * sRS + row0 + line];
          if (EGELU)     xv = 0.5f * xv * (1.0f + erff(xv * 0.70710678118f));
          u16 u;
          if (OUTMODE == 2) { union { u16 s; _Float16 h; } cu; cu.h = (_Float16)xv; u = cu.s; }
          else u = f2bf(xv);
          *(u16*)(sm + ((line * 256 + pc) ^ ((line & 7) << 4))) = u;
        }
      }
    }
    __syncthreads();
    u16* Cb = (u16*)(OUTMODE == 3 ? (sel ? C1 : C0) : C0) + (size_t)z * sC + oc0;
#pragma unroll
    for (int i = 0; i < 8; ++i) {
      const int o = i * 4096 + tid * 16;
      const int line = o >> 8, ps = o & 255;
      f32x4 v = *(const f32x4*)(sm + ((line * 256 + ps) ^ ((line & 7) << 4)));
      *(f32x4*)((char*)(Cb + (size_t)(row0 + line) * ldc) + ps) = v;
    }
  }
}

// ---------------------------------------------------------------------------
// BK=64 A/B variant (MLP1 only): 128x128 tile, 4 waves (2x2), per-wave
// 64x64, BK=64 -> 16 K-steps (half the barrier events), 32 MFMA/step in two
// 16-MFMA half-K sub-phases. 2 x 32KB LDS ring (64KB -> 2 blocks/CU).
// 128B-row swizzle family (R15-verified): store unit (l&7)^((l>>3)&7) from
// pre-swizzled global; read unit (h*4+s)^(fr&7). R5-proven step shape:
// stage t+1 at top, lgkmcnt(0) per sub-phase, one vmcnt(0)+barrier per step.
// ---------------------------------------------------------------------------
template<int EGELU>
__global__ __launch_bounds__(256, 2)
void gemm128k64(const u16* __restrict__ A, const u16* __restrict__ B,
                const float* __restrict__ bias, void* __restrict__ C,
                int K, int lda, int ldb, int ldc)
{
  __shared__ __align__(1024) u16 smem[32768];   // 64 KB

  const int gx = gridDim.x, gy = gridDim.y;
  const int nwg = gx * gy;
  const int orig = blockIdx.y * gx + blockIdx.x;
  const int q = nwg >> 3, r = nwg & 7;
  const int xcd = orig & 7, pos0 = orig >> 3;
  const int wg = (xcd < r ? xcd * (q + 1) : r * (q + 1) + (xcd - r) * q) + pos0;
  int bx, by;
  if ((gx & 3) == 0) {
    const int rr = wg % (gy << 2);
    bx = (wg / (gy << 2)) * 4 + (rr & 3);
    by = rr >> 2;
  } else {
    bx = wg % gx; by = wg / gx;
  }
  const int row0 = by * 128, col0 = bx * 128;

  const int nkt = K >> 6;                 // 16 for K=1024
  const int tid = threadIdx.x, wid = tid >> 6, lane = tid & 63;
  const int wr = wid >> 1, wc = wid & 1;
  const int fr = lane & 15, s = lane >> 4;

  // staging: wave wid covers rows wid*32..wid*32+31 of A and of B.
  // lane l -> row +(l>>3), 16B-unit (l&7)^((l>>3)&7) (pre-swizzled source;
  // gload16's linear dest then yields LDS[row][u] = global[row][u^(row&7)]).
  const int l8 = lane >> 3;
  const int u8 = (lane & 7) ^ (l8 & 7);
  const char* gA = (const char*)A + ((size_t)(row0 + wid * 32 + l8) * lda + u8 * 8) * 2;
  const char* gB = (const char*)B + ((size_t)(col0 + wid * 32 + l8) * ldb + u8 * 8) * 2;
  const size_t lda8 = (size_t)8 * lda * 2;
  const size_t ldb8 = (size_t)8 * ldb * 2;
  const unsigned sbase = (unsigned)(unsigned long long)(void*)smem;

  // buffer: A 16KB @0 (row r at r*128), B 16KB @16384
  #define STG64(t2, bo) { char* la = (char*)smem + (bo) + wid * 4096;          \
      char* lb2 = (char*)smem + (bo) + 16384 + wid * 4096;                     \
      size_t kb = (size_t)(t2) * 128;                                          \
      gload16(gA + kb,            la);                                         \
      gload16(gA + kb +     lda8, la + 1024);                                  \
      gload16(gA + kb + 2 * lda8, la + 2048);                                  \
      gload16(gA + kb + 3 * lda8, la + 3072);                                  \
      gload16(gB + kb,            lb2);                                        \
      gload16(gB + kb +     ldb8, lb2 + 1024);                                 \
      gload16(gB + kb + 2 * ldb8, lb2 + 2048);                                 \
      gload16(gB + kb + 3 * ldb8, lb2 + 3072); }

  // read frag: row*128 + ((h*4+s)^(fr&7))*16
  #define RDAF(h) _Pragma("unroll") for (int m = 0; m < 4; ++m)                \
      af[m] = dsr128(sbase + cbo + (unsigned)((wr * 64 + m * 16 + fr) * 128 +  \
                     ((((h) * 4 + s) ^ (fr & 7)) << 4)));
  #define RDBF(h) _Pragma("unroll") for (int n = 0; n < 4; ++n)                \
      bf[n] = dsr128(sbase + cbo + 16384u + (unsigned)((wc * 64 + n * 16 + fr) * 128 + \
                     ((((h) * 4 + s) ^ (fr & 7)) << 4)));

  f32x4 acc[4][4] = {};

  STG64(0, 0);
  asm volatile("s_waitcnt vmcnt(0)");
  asm volatile("s_barrier" ::: "memory");

  unsigned cbo = 0;
  for (int t = 0; t < nkt; ++t) {
    if (t + 1 < nkt) STG64(t + 1, cbo ^ 16384u ^ 49152u);   // other buffer
    // NOTE: other buffer offset = cbo ^ 32768? buffers at 0 and 32768? No:
    // buffers are 32KB each at 0 and 32768 -> other = cbo ^ 32768.
    bf16x8 af[4], bf[4];
    // half 0
    RDAF(0); RDBF(0);
    asm volatile("s_waitcnt lgkmcnt(0)");
    __builtin_amdgcn_sched_barrier(0);
    __builtin_amdgcn_s_setprio(1);
#pragma unroll
    for (int m = 0; m < 4; ++m)
#pragma unroll
      for (int n = 0; n < 4; ++n)
        acc[m][n] = __builtin_amdgcn_mfma_f32_16x16x32_bf16(af[m], bf[n], acc[m][n], 0, 0, 0);
    __builtin_amdgcn_s_setprio(0);
    // half 1
    RDAF(1); RDBF(1);
    asm volatile("s_waitcnt lgkmcnt(0)");
    __builtin_amdgcn_sched_barrier(0);
    __builtin_amdgcn_s_setprio(1);
#pragma unroll
    for (int m = 0; m < 4; ++m)
#pragma unroll
      for (int n = 0; n < 4; ++n)
        acc[m][n] = __builtin_amdgcn_mfma_f32_16x16x32_bf16(af[m], bf[n], acc[m][n], 0, 0, 0);
    __builtin_amdgcn_s_setprio(0);
    asm volatile("s_waitcnt vmcnt(0)");
    asm volatile("s_barrier" ::: "memory");
    cbo ^= 32768u;
  }
  #undef STG64
  #undef RDAF
  #undef RDBF

  // ---- epilogue via LDS (bf16 + bias + GELU), 128 lines x 256 B ----
  char* sm = (char*)smem;
  const int r4 = s * 4;
#pragma unroll
  for (int n = 0; n < 4; ++n) {
    const int col = col0 + wc * 64 + n * 16 + fr;
    const int pc = (wc * 64 + n * 16 + fr) * 2;
    const float bia = bias[col];
#pragma unroll
    for (int m = 0; m < 4; ++m) {
#pragma unroll
      for (int j = 0; j < 4; ++j) {
        const int line = wr * 64 + m * 16 + r4 + j;
        float xv = acc[m][n][j] + bia;
        if (EGELU) xv = 0.5f * xv * (1.0f + erff(xv * 0.70710678118f));
        *(u16*)(sm + ((line * 256 + pc) ^ ((line & 7) << 4))) = f2bf(xv);
      }
    }
  }
  __syncthreads();
  u16* Cb = (u16*)C + col0;
#pragma unroll
  for (int i = 0; i < 8; ++i) {
    const int o = i * 4096 + tid * 16;
    const int line = o >> 8, ps = o & 255;
    f32x4 v = *(const f32x4*)(sm + ((line * 256 + ps) ^ ((line & 7) << 4)));
    *(f32x4*)((char*)(Cb + (size_t)(row0 + line) * ldc) + ps) = v;
  }
}

// single fused f32->bf16 convert: x -> out_x, weights -> out_w (contiguous)
__global__ __launch_bounds__(256) void cvt_all_k(
    const float* __restrict__ x,  const float* __restrict__ wq,
    const float* __restrict__ wk, const float* __restrict__ wv,
    const float* __restrict__ w1, const float* __restrict__ w2,
    u16* __restrict__ out_x, u16* __restrict__ out_w)
{
  const int i = blockIdx.x * 256 + threadIdx.x;   // float4 index
  const float* src; int off; u16* dst; int dofs;
  if (i < 4194304)      { src = x;  off = i;           dst = out_x; dofs = i; }
  else if (i < 4456448) { src = wq; off = i - 4194304; dst = out_w; dofs = i - 4194304; }
  else if (i < 4718592) { src = wk; off = i - 4456448; dst = out_w; dofs = i - 4194304; }
  else if (i < 4980736) { src = wv; off = i - 4718592; dst = out_w; dofs = i - 4194304; }
  else if (i < 6029312) { src = w1; off = i - 4980736; dst = out_w; dofs = i - 4194304; }
  else                  { src = w2; off = i - 6029312; dst = out_w; dofs = i - 4194304; }
  float4 v = ((const float4*)src)[off];
  u16x4 o;
  o.x = f2bf(v.x); o.y = f2bf(v.y); o.z = f2bf(v.z); o.w = f2bf(v.w);
  ((u16x4*)dst)[dofs] = o;
}

// batched row softmax over f16 scores -> unnormalized bf16 P + 1/sum
__global__ __launch_bounds__(256) void softmax_k(u16* __restrict__ sc, float* __restrict__ rinv, int rows0) {
  const int widx = blockIdx.x * 4 + (threadIdx.x >> 6);
  const int lane = threadIdx.x & 63;
  u16* row = sc + (size_t)widx * SS;
  const int L = (widx & (SS - 1)) + 1;
  float mx = -1e30f;
  for (int k = 0; k < 4; ++k) {
    const int j0 = k * 512 + lane * 8;
    if (j0 < L) {
      u16x8 v = *(const u16x8*)(row + j0);
      int lim = L - j0; if (lim > 8) lim = 8;
#pragma unroll
      for (int e = 0; e < 8; ++e) {
        if (e < lim) { union { u16 u; _Float16 h; } c; c.u = v[e]; mx = fmaxf(mx, (float)c.h); }
      }
    }
  }
#pragma unroll
  for (int o = 32; o >= 1; o >>= 1) mx = fmaxf(mx, __shfl_xor(mx, o));
  float sacc = 0.0f;
  for (int k = 0; k < 4; ++k) {
    const int j0 = k * 512 + lane * 8;
    u16x8 v = *(const u16x8*)(row + j0);
    u16x8 w;
#pragma unroll
    for (int e = 0; e < 8; ++e) {
      const int j = j0 + e;
      float ev = 0.0f;
      if (j < L) { union { u16 u; _Float16 h; } c; c.u = v[e]; ev = __expf((float)c.h - mx); sacc += ev; }
      w[e] = f2bf(ev);
    }
    *(u16x8*)(row + j0) = w;
  }
#pragma unroll
  for (int o = 32; o >= 1; o >>= 1) sacc += __shfl_xor(sacc, o);
  if (lane == 0) rinv[rows0 + widx] = 1.0f / sacc;
}

extern "C" void kernel_launch(void* const* d_in, const int* in_sizes, int n_in,
                              void* d_out, int out_size, void* d_ws, size_t ws_size,
                              hipStream_t stream) {
  const float* x  = (const float*)d_in[0];
  const float* Wq = (const float*)d_in[1];
  const float* bq = (const float*)d_in[2];
  const float* Wk = (const float*)d_in[3];
  const float* bk = (const float*)d_in[4];
  const float* Wv = (const float*)d_in[5];
  const float* bv = (const float*)d_in[6];
  const float* W1 = (const float*)d_in[7];
  const float* b1 = (const float*)d_in[8];
  const float* W2 = (const float*)d_in[9];
  const float* b2 = (const float*)d_in[10];

  char* ws = (char*)d_ws;
  u16*  Qb   = (u16*)(ws);                          // 32 MB; att overwrites
  u16*  Kb   = (u16*)(ws + 33554432);               // 32 MB; h overwrites
  u16*  Vtb  = (u16*)(ws + 67108864);               // 32 MB
  u16*  big  = (u16*)(ws + 100663296);              // scores/P 64 MB; xb first
  float* rinv = (float*)(ws + 167772160);           // 64 KB
  u16*  Wcat = (u16*)(ws + 167772160 + 65536);      // 6 MB
  u16*  W1b  = Wcat + 3 * DD * DD;                  // 8 MB
  u16*  W2b  = W1b + DFFN * DD;                     // 8 MB
  u16*  xb   = big;
  u16*  att  = Qb;
  u16*  h    = Kb;                                  // 128 MB over Kb|Vtb|big

  cvt_all_k<<<27648, 256, 0, stream>>>(x, Wq, Wk, Wv, W1, W2, xb, Wcat);

  // fused QKV projection: N = 3072, grid 24 x 128
  gemm128<1,0,0,0,3,0,0><<<dim3(3 * DD / 128, MTOT / 128), 256, 0, stream>>>(
      xb, Wcat, bq, bk, bv, nullptr, (void*)Qb, (void*)Kb, (void*)Vtb,
      DD, DD, DD, DD, 0.f, 0, 0, 0, 0);

  // attention, all batches
  gemm128<0,0,1,0,2,1,0><<<dim3(SS/128, SS/128, NB), 256, 0, stream>>>(
      Qb, Kb, nullptr, nullptr, nullptr, nullptr, (void*)big, nullptr, nullptr,
      DD, DD, DD, SS, 0.03125f,
      (long long)SS * DD, (long long)SS * DD, (long long)SS * SS, 0);
  softmax_k<<<NB * SS / 4, 256, 0, stream>>>(big, rinv, 0);
  gemm128<0,0,0,1,0,0,1><<<dim3(DD/128, SS/128, NB), 256, 0, stream>>>(
      big, Vtb, nullptr, nullptr, nullptr, rinv,
      (void*)att, nullptr, nullptr,
      SS, SS, SS, DD, 0.f,
      (long long)SS * SS, (long long)DD * SS, (long long)SS * DD, SS);

  // MLP1 via BK=64 A/B kernel; MLP2 on champion
  gemm128k64<1><<<dim3(DFFN/128, MTOT/128), 256, 0, stream>>>(
      att, W1b, b1, (void*)h, DD, DD, DD, DFFN);
  gemm128<1,0,0,0,1,0,0><<<dim3(DD/128, MTOT/128), 256, 0, stream>>>(
      h, W2b, b2, nullptr, nullptr, nullptr,
      (void*)d_out, nullptr, nullptr,
      DFFN, DFFN, DFFN, DD, 0.f, 0, 0, 0, 0);
}

// Round 21
// 679.407 us; speedup vs baseline: 1.0630x; 1.0630x over previous
//
#include <hip/hip_runtime.h>
#include <hip/hip_bf16.h>

#define NB   8
#define SS   2048
#define DD   1024
#define DFFN 4096
#define MTOT (NB*SS)   // 16384

typedef unsigned short u16;
typedef __attribute__((ext_vector_type(4))) float f32x4;
typedef __attribute__((ext_vector_type(8))) short bf16x8;
typedef __attribute__((ext_vector_type(4))) int i32x4;
typedef __attribute__((ext_vector_type(4))) unsigned short u16x4;
typedef __attribute__((ext_vector_type(8))) unsigned short u16x8;

__device__ __forceinline__ u16 f2bf(float f) {
  union { float f; unsigned u; } c; c.f = f;
  unsigned r = c.u + 0x7FFFu + ((c.u >> 16) & 1u);
  return (u16)(r >> 16);
}

__device__ __forceinline__ void gload16(const void* g, void* l) {
  __builtin_amdgcn_global_load_lds(
      (const __attribute__((address_space(1))) void*)(unsigned long long)g,
      (__attribute__((address_space(3))) void*)(unsigned)(unsigned long long)l,
      16, 0, 0);
}

// opaque ds_read_b128 (manual lgkmcnt/vmcnt accounting)
__device__ __forceinline__ bf16x8 dsr128(unsigned addr) {
  i32x4 r;
  asm volatile("ds_read_b128 %0, %1" : "=v"(r) : "v"(addr));
  return __builtin_bit_cast(bf16x8, r);
}

// ---------------------------------------------------------------------------
// FINAL champion (R17 config, measured 677us): 128x128 GEMM-BT, 4 waves
// (2x2), per-wave 64x64, BK=32, 3-buffer LDS ring (48KB), stage t+2,
// counted vmcnt(4). Swizzled staging (0 bank conflicts), LDS-staged epilogue
// (full-line stores), bijective XCD swizzle + width-4 supertile.
// Tested-and-closed: 256^2 tiles (R2-4/14-15), 5 waves (R10 spill), BK=64
// (R20), barrier-free (R9), B-in-reg (R7), width-8 supertile (R18).
// OUTMODE: 0=bf16, 1=f32, 2=f16, 3=QKV fused (Q,K bf16 rows + V transposed).
// ---------------------------------------------------------------------------
template<int EBIAS, int EGELU, int ESCALE, int EROWSCALE, int OUTMODE, int CSKIP, int CK>
__global__ __launch_bounds__(256, 4)
void gemm128(const u16* __restrict__ A, const u16* __restrict__ B,
             const float* __restrict__ bias0, const float* __restrict__ bias1,
             const float* __restrict__ bias2, const float* __restrict__ rowscale,
             void* __restrict__ C0, void* __restrict__ C1, void* __restrict__ C2,
             int K, int lda, int ldb, int ldc, float scale,
             long long sA, long long sB, long long sC, int sRS)
{
  __shared__ __align__(1024) u16 smem[24576];   // 48 KB (3-ring; epilogue reuse)

  const int gx = gridDim.x, gy = gridDim.y;
  const int nwg = gx * gy;
  const int orig = blockIdx.y * gx + blockIdx.x;
  const int q = nwg >> 3, r = nwg & 7;
  const int xcd = orig & 7, pos0 = orig >> 3;
  const int wg = (xcd < r ? xcd * (q + 1) : r * (q + 1) + (xcd - r) * q) + pos0;
  int bx, by;
  if ((gx & 3) == 0) {               // supertile: 4-col stripes (bijective)
    const int rr = wg % (gy << 2);
    bx = (wg / (gy << 2)) * 4 + (rr & 3);
    by = rr >> 2;
  } else {
    bx = wg % gx; by = wg / gx;
  }
  const int row0 = by * 128, col0 = bx * 128;
  if (CSKIP && col0 > row0 + 127) return;

  const int z = blockIdx.z;
  A += (size_t)z * sA;
  B += (size_t)z * sB;

  int nkt = K >> 5;
  if (CK) { int lim = (row0 + 128) >> 5; if (lim < nkt) nkt = lim; }
  // all instantiations have nkt >= 4

  const int tid  = threadIdx.x;
  const int wid  = tid >> 6;
  const int lane = tid & 63;
  const int wr = wid >> 1, wc = wid & 1;

  const int srow = wid * 16 + (lane >> 2);
  const int sunit = (lane & 3) ^ ((lane >> 3) & 3);
  const char* gA = (const char*)A + ((size_t)(row0 + srow) * lda + sunit * 8) * 2;
  const char* gB = (const char*)B + ((size_t)(col0 + srow) * ldb + sunit * 8) * 2;
  const size_t ldab = (size_t)64 * lda * 2;
  const size_t ldbb = (size_t)64 * ldb * 2;

  // stage K-step t2 into ring slot at byte offset bo (0/16384/32768)
  #define STG(t2, bo) { char* lb = (char*)smem + (bo); size_t kb = (size_t)(t2) * 64; \
      gload16(gA + kb,        lb + wid * 1024);                                       \
      gload16(gA + kb + ldab, lb + 4096 + wid * 1024);                                \
      gload16(gB + kb,        lb + 8192 + wid * 1024);                                \
      gload16(gB + kb + ldbb, lb + 8192 + 4096 + wid * 1024); }

  const int fr = lane & 15;
  const int ks16 = ((lane >> 4) & 3) * 16;
  const int xm = ((lane >> 1) & 3) << 4;
  const unsigned sbase = (unsigned)(unsigned long long)(void*)smem;

  f32x4 acc[4][4] = {};

  // prologue: stage tiles 0 (slot0) and 1 (slot1); vmcnt(4) -> tile 0 landed
  STG(0, 0); STG(1, 16384);
  asm volatile("s_waitcnt vmcnt(4)");
  asm volatile("s_barrier" ::: "memory");

  unsigned cbo = 0, sbo = 32768;   // compute / stage ring offsets

  #define KSTEP_BODY(WAITN)                                                    \
    bf16x8 af[4], bf[4];                                                       \
    _Pragma("unroll") for (int m = 0; m < 4; ++m)                              \
      af[m] = dsr128(sbase + cbo + (((wr * 64 + m * 16 + fr) * 64 + ks16) ^ xm)); \
    _Pragma("unroll") for (int n = 0; n < 4; ++n)                              \
      bf[n] = dsr128(sbase + cbo + ((8192 + (wc * 64 + n * 16 + fr) * 64 + ks16) ^ xm)); \
    asm volatile("s_waitcnt lgkmcnt(0)");                                      \
    __builtin_amdgcn_sched_barrier(0);                                         \
    __builtin_amdgcn_s_setprio(1);                                             \
    _Pragma("unroll") for (int m = 0; m < 4; ++m)                              \
      _Pragma("unroll") for (int n = 0; n < 4; ++n)                            \
        acc[m][n] = __builtin_amdgcn_mfma_f32_16x16x32_bf16(af[m], bf[n], acc[m][n], 0, 0, 0); \
    __builtin_amdgcn_s_setprio(0);                                             \
    asm volatile("s_waitcnt vmcnt(" #WAITN ")");                               \
    asm volatile("s_barrier" ::: "memory");                                    \
    cbo += 16384; if (cbo == 49152) cbo = 0;                                   \
    sbo += 16384; if (sbo == 49152) sbo = 0;

  // main loop: stage t+2; vmcnt(4) -> tile t+1 landed, t+2's 4 in flight
  for (int t = 0; t < nkt - 2; ++t) {
    STG(t + 2, sbo);
    KSTEP_BODY(4)
  }
  // tail: last 2 steps, nothing newer staged -> vmcnt(0)
  { KSTEP_BODY(0) }
  { KSTEP_BODY(0) }
  #undef KSTEP_BODY
  #undef STG

  // ---- epilogue via LDS ----
  char* sm = (char*)smem;
  const int r4 = (lane >> 4) * 4;
  const int sel  = (OUTMODE == 3) ? (col0 >> 10) : 0;
  const int oc0  = (OUTMODE == 3) ? (col0 & 1023) : col0;
  const float* bias = (OUTMODE == 3) ? (sel == 0 ? bias0 : sel == 1 ? bias1 : bias2)
                                     : bias0;

  if (OUTMODE == 1) {
#pragma unroll
    for (int p = 0; p < 2; ++p) {
      if (wc == p) {
#pragma unroll
        for (int n = 0; n < 4; ++n) {
          const int col = oc0 + wc * 64 + n * 16 + fr;
          const int pb = (n * 16 + fr) * 4;
          float bia = EBIAS ? bias[col] : 0.0f;
#pragma unroll
          for (int m = 0; m < 4; ++m) {
#pragma unroll
            for (int j = 0; j < 4; ++j) {
              const int line = wr * 64 + m * 16 + r4 + j;
              float xv = acc[m][n][j];
              if (EBIAS)     xv += bia;
              if (ESCALE)    xv *= scale;
              if (EROWSCALE) xv *= rowscale[z * sRS + row0 + line];
              if (EGELU)     xv = 0.5f * xv * (1.0f + erff(xv * 0.70710678118f));
              *(float*)(sm + ((line * 256 + pb) ^ ((line & 7) << 4))) = xv;
            }
          }
        }
      }
      __syncthreads();
      float* Cb = (float*)C0 + (size_t)z * sC;
#pragma unroll
      for (int i = 0; i < 8; ++i) {
        const int o = i * 4096 + tid * 16;
        const int line = o >> 8, ps = o & 255;
        f32x4 v = *(const f32x4*)(sm + ((line * 256 + ps) ^ ((line & 7) << 4)));
        *(f32x4*)((char*)(Cb + (size_t)(row0 + line) * ldc + oc0 + p * 64) + ps) = v;
      }
      __syncthreads();
    }
  } else if (OUTMODE == 3 && sel == 2) {
#pragma unroll
    for (int n = 0; n < 4; ++n) {
      const int line = wc * 64 + n * 16 + fr;
      float bia = EBIAS ? bias[oc0 + line] : 0.0f;
#pragma unroll
      for (int m = 0; m < 4; ++m) {
        const int rb = wr * 64 + m * 16 + r4;
        u16x4 pk;
#pragma unroll
        for (int j = 0; j < 4; ++j) pk[j] = f2bf(acc[m][n][j] + bia);
        *(u16x4*)(sm + ((line * 256 + rb * 2) ^ ((line & 7) << 4))) = pk;
      }
    }
    __syncthreads();
    u16* Cb = (u16*)C2 + (size_t)(row0 >> 11) * (DD * SS) + (row0 & (SS - 1));
#pragma unroll
    for (int i = 0; i < 8; ++i) {
      const int o = i * 4096 + tid * 16;
      const int line = o >> 8, ps = o & 255;
      f32x4 v = *(const f32x4*)(sm + ((line * 256 + ps) ^ ((line & 7) << 4)));
      *(f32x4*)((char*)(Cb + (size_t)(oc0 + line) * SS) + ps) = v;
    }
  } else {
#pragma unroll
    for (int n = 0; n < 4; ++n) {
      const int col = oc0 + wc * 64 + n * 16 + fr;
      const int pc = (wc * 64 + n * 16 + fr) * 2;
      float bia = EBIAS ? bias[col] : 0.0f;
#pragma unroll
      for (int m = 0; m < 4; ++m) {
#pragma unroll
        for (int j = 0; j < 4; ++j) {
          const int line = wr * 64 + m * 16 + r4 + j;
          float xv = acc[m][n][j];
          if (EBIAS)     xv += bia;
          if (ESCALE)    xv *= scale;
          if (EROWSCALE) xv *= rowscale[z * sRS + row0 + line];
          if (EGELU)     xv = 0.5f * xv * (1.0f + erff(xv * 0.70710678118f));
          u16 u;
          if (OUTMODE == 2) { union { u16 s; _Float16 h; } cu; cu.h = (_Float16)xv; u = cu.s; }
          else u = f2bf(xv);
          *(u16*)(sm + ((line * 256 + pc) ^ ((line & 7) << 4))) = u;
        }
      }
    }
    __syncthreads();
    u16* Cb = (u16*)(OUTMODE == 3 ? (sel ? C1 : C0) : C0) + (size_t)z * sC + oc0;
#pragma unroll
    for (int i = 0; i < 8; ++i) {
      const int o = i * 4096 + tid * 16;
      const int line = o >> 8, ps = o & 255;
      f32x4 v = *(const f32x4*)(sm + ((line * 256 + ps) ^ ((line & 7) << 4)));
      *(f32x4*)((char*)(Cb + (size_t)(row0 + line) * ldc) + ps) = v;
    }
  }
}

// single fused f32->bf16 convert: x -> out_x, weights -> out_w (contiguous)
__global__ __launch_bounds__(256) void cvt_all_k(
    const float* __restrict__ x,  const float* __restrict__ wq,
    const float* __restrict__ wk, const float* __restrict__ wv,
    const float* __restrict__ w1, const float* __restrict__ w2,
    u16* __restrict__ out_x, u16* __restrict__ out_w)
{
  const int i = blockIdx.x * 256 + threadIdx.x;   // float4 index
  const float* src; int off; u16* dst; int dofs;
  if (i < 4194304)      { src = x;  off = i;           dst = out_x; dofs = i; }
  else if (i < 4456448) { src = wq; off = i - 4194304; dst = out_w; dofs = i - 4194304; }
  else if (i < 4718592) { src = wk; off = i - 4456448; dst = out_w; dofs = i - 4194304; }
  else if (i < 4980736) { src = wv; off = i - 4718592; dst = out_w; dofs = i - 4194304; }
  else if (i < 6029312) { src = w1; off = i - 4980736; dst = out_w; dofs = i - 4194304; }
  else                  { src = w2; off = i - 6029312; dst = out_w; dofs = i - 4194304; }
  float4 v = ((const float4*)src)[off];
  u16x4 o;
  o.x = f2bf(v.x); o.y = f2bf(v.y); o.z = f2bf(v.z); o.w = f2bf(v.w);
  ((u16x4*)dst)[dofs] = o;
}

// batched row softmax over f16 scores -> unnormalized bf16 P + 1/sum
__global__ __launch_bounds__(256) void softmax_k(u16* __restrict__ sc, float* __restrict__ rinv, int rows0) {
  const int widx = blockIdx.x * 4 + (threadIdx.x >> 6);
  const int lane = threadIdx.x & 63;
  u16* row = sc + (size_t)widx * SS;
  const int L = (widx & (SS - 1)) + 1;
  float mx = -1e30f;
  for (int k = 0; k < 4; ++k) {
    const int j0 = k * 512 + lane * 8;
    if (j0 < L) {
      u16x8 v = *(const u16x8*)(row + j0);
      int lim = L - j0; if (lim > 8) lim = 8;
#pragma unroll
      for (int e = 0; e < 8; ++e) {
        if (e < lim) { union { u16 u; _Float16 h; } c; c.u = v[e]; mx = fmaxf(mx, (float)c.h); }
      }
    }
  }
#pragma unroll
  for (int o = 32; o >= 1; o >>= 1) mx = fmaxf(mx, __shfl_xor(mx, o));
  float sacc = 0.0f;
  for (int k = 0; k < 4; ++k) {
    const int j0 = k * 512 + lane * 8;
    u16x8 v = *(const u16x8*)(row + j0);
    u16x8 w;
#pragma unroll
    for (int e = 0; e < 8; ++e) {
      const int j = j0 + e;
      float ev = 0.0f;
      if (j < L) { union { u16 u; _Float16 h; } c; c.u = v[e]; ev = __expf((float)c.h - mx); sacc += ev; }
      w[e] = f2bf(ev);
    }
    *(u16x8*)(row + j0) = w;
  }
#pragma unroll
  for (int o = 32; o >= 1; o >>= 1) sacc += __shfl_xor(sacc, o);
  if (lane == 0) rinv[rows0 + widx] = 1.0f / sacc;
}

extern "C" void kernel_launch(void* const* d_in, const int* in_sizes, int n_in,
                              void* d_out, int out_size, void* d_ws, size_t ws_size,
                              hipStream_t stream) {
  const float* x  = (const float*)d_in[0];
  const float* Wq = (const float*)d_in[1];
  const float* bq = (const float*)d_in[2];
  const float* Wk = (const float*)d_in[3];
  const float* bk = (const float*)d_in[4];
  const float* Wv = (const float*)d_in[5];
  const float* bv = (const float*)d_in[6];
  const float* W1 = (const float*)d_in[7];
  const float* b1 = (const float*)d_in[8];
  const float* W2 = (const float*)d_in[9];
  const float* b2 = (const float*)d_in[10];

  char* ws = (char*)d_ws;
  u16*  Qb   = (u16*)(ws);                          // 32 MB; att overwrites
  u16*  Kb   = (u16*)(ws + 33554432);               // 32 MB; h overwrites
  u16*  Vtb  = (u16*)(ws + 67108864);               // 32 MB
  u16*  big  = (u16*)(ws + 100663296);              // scores/P 64 MB; xb first
  float* rinv = (float*)(ws + 167772160);           // 64 KB
  u16*  Wcat = (u16*)(ws + 167772160 + 65536);      // 6 MB
  u16*  W1b  = Wcat + 3 * DD * DD;                  // 8 MB
  u16*  W2b  = W1b + DFFN * DD;                     // 8 MB
  u16*  xb   = big;
  u16*  att  = Qb;
  u16*  h    = Kb;                                  // 128 MB over Kb|Vtb|big

  cvt_all_k<<<27648, 256, 0, stream>>>(x, Wq, Wk, Wv, W1, W2, xb, Wcat);

  // fused QKV projection: N = 3072, grid 24 x 128
  gemm128<1,0,0,0,3,0,0><<<dim3(3 * DD / 128, MTOT / 128), 256, 0, stream>>>(
      xb, Wcat, bq, bk, bv, nullptr, (void*)Qb, (void*)Kb, (void*)Vtb,
      DD, DD, DD, DD, 0.f, 0, 0, 0, 0);

  // attention, all batches
  gemm128<0,0,1,0,2,1,0><<<dim3(SS/128, SS/128, NB), 256, 0, stream>>>(
      Qb, Kb, nullptr, nullptr, nullptr, nullptr, (void*)big, nullptr, nullptr,
      DD, DD, DD, SS, 0.03125f,
      (long long)SS * DD, (long long)SS * DD, (long long)SS * SS, 0);
  softmax_k<<<NB * SS / 4, 256, 0, stream>>>(big, rinv, 0);
  gemm128<0,0,0,1,0,0,1><<<dim3(DD/128, SS/128, NB), 256, 0, stream>>>(
      big, Vtb, nullptr, nullptr, nullptr, rinv,
      (void*)att, nullptr, nullptr,
      SS, SS, SS, DD, 0.f,
      (long long)SS * SS, (long long)DD * SS, (long long)SS * DD, SS);

  // MLP full-M
  gemm128<1,1,0,0,0,0,0><<<dim3(DFFN/128, MTOT/128), 256, 0, stream>>>(
      att, W1b, b1, nullptr, nullptr, nullptr,
      (void*)h, nullptr, nullptr,
      DD, DD, DD, DFFN, 0.f, 0, 0, 0, 0);
  gemm128<1,0,0,0,1,0,0><<<dim3(DD/128, MTOT/128), 256, 0, stream>>>(
      h, W2b, b2, nullptr, nullptr, nullptr,
      (void*)d_out, nullptr, nullptr,
      DFFN, DFFN, DFFN, DD, 0.f, 0, 0, 0, 0);
}